// Round 16
// baseline (352.419 us; speedup 1.0000x reference)
//
#include <hip/hip_runtime.h>
#include <math.h>
#include <type_traits>

#define NNODES 100000
#define NEDGES 1600000
#define NGRAPH 128
#define NBKT 391          // dst buckets of 256 nodes
#define CAP 1536          // per (partition,bucket) capacity
#define EPB 2048          // edges per bucketA block

typedef _Float16 f16x4 __attribute__((ext_vector_type(4)));
typedef _Float16 f16x8 __attribute__((ext_vector_type(8)));
typedef float f32x4 __attribute__((ext_vector_type(4)));

// ---- front1: weight convert + alpha GEMV (blocks 0-201)  ||  bucketA (202+) ----
__global__ __launch_bounds__(256) void front1(
    const float* __restrict__ w1, const float* __restrict__ w2,
    const float* __restrict__ as1c, const float* __restrict__ ad1c,
    const float* __restrict__ as2c, const float* __restrict__ ad2c,
    _Float16* __restrict__ w1h, _Float16* __restrict__ w2h,
    _Float16* __restrict__ va1, _Float16* __restrict__ va2,
    const int* __restrict__ srcv, const int* __restrict__ dstv,
    unsigned* __restrict__ part, int* __restrict__ gcur, int e_count) {
  __shared__ int hist[NBKT];
  __shared__ int base_[NBKT];
  __shared__ int lofs[NBKT];
  const int tid = threadIdx.x;
  if (blockIdx.x < 202) {
    const int b = blockIdx.x;
    if (b < 8) {
      if (tid < 128) {
        int h = b & 3;
        const float* coef = (b >= 4) ? ad1c : as1c;
        float s = 0.f;
        for (int c = 0; c < 64; ++c)
          s = fmaf(w1[(size_t)(h * 64 + c) * 128 + tid], coef[h * 64 + c], s);
        va1[b * 128 + tid] = (_Float16)s;
        va1[(b + 8) * 128 + tid] = (_Float16)0.f;
      }
    } else if (b < 10) {
      int r = b - 8;
      const float* coef = r ? ad2c : as2c;
      float s = 0.f;
      for (int c = 0; c < 64; ++c) s = fmaf(w2[(size_t)c * 256 + tid], coef[c], s);
      va2[r * 256 + tid] = (_Float16)s;
      for (int z = 2 + r * 7; z < 9 + r * 7; ++z) va2[z * 256 + tid] = (_Float16)0.f;
    } else if (b < 138) {
      int i = (b - 10) * 256 + tid;
      w1h[i] = (_Float16)w1[i];
    } else {
      int i = (b - 138) * 256 + tid;
      w2h[i] = (_Float16)w2[i];
    }
    return;
  }
  const int ab = blockIdx.x - 202;
  const int P = ab & 7;
  for (int i = tid; i < NBKT; i += 256) { hist[i] = 0; lofs[i] = 0; }
  __syncthreads();
  const int e0 = ab * EPB;
  const int e1 = min(e0 + EPB, e_count);
  for (int e = e0 + tid; e < e1; e += 256) atomicAdd(&hist[dstv[e] >> 8], 1);
  __syncthreads();
  for (int i = tid; i < NBKT; i += 256) {
    int c = hist[i];
    base_[i] = c ? atomicAdd(&gcur[(P * NBKT + i) * 16], c) : 0;
  }
  __syncthreads();
  for (int e = e0 + tid; e < e1; e += 256) {
    int d = dstv[e];
    int b = d >> 8;
    int l = atomicAdd(&lofs[b], 1);
    part[(size_t)(P * NBKT + b) * CAP + base_[b] + l] =
        ((unsigned)srcv[e] << 8) | (unsigned)(d & 255);
  }
}

// ---- bucketB1p: per-node degree count + in-bucket exclusive prefix + bucket sum -
__global__ __launch_bounds__(256) void bucketB1p(const unsigned* __restrict__ part,
    const int* __restrict__ gcur, int* __restrict__ pre, int* __restrict__ bsum, int n) {
  __shared__ int cnt[256];
  __shared__ int sc[256];
  const int b = blockIdx.x, tid = threadIdx.x;
  cnt[tid] = 0;
  __syncthreads();
  for (int P = 0; P < 8; ++P) {
    int cn = gcur[(P * NBKT + b) * 16];
    const unsigned* seg = part + (size_t)(P * NBKT + b) * CAP;
    for (int i = tid; i < cn; i += 256) atomicAdd(&cnt[seg[i] & 255], 1);
  }
  __syncthreads();
  int own = cnt[tid];
  sc[tid] = own;
  __syncthreads();
  for (int o = 1; o < 256; o <<= 1) {
    int t = (tid >= o) ? sc[tid - o] : 0;
    __syncthreads();
    sc[tid] += t;
    __syncthreads();
  }
  int node = (b << 8) + tid;
  if (node < n) pre[node] = sc[tid] - own;
  if (tid == 255) bsum[b] = sc[255];
}

// ---- bucketB2: derive offsets (cross-bucket base from bsum) + place esrc --------
__global__ __launch_bounds__(256) void bucketB2(const unsigned* __restrict__ part,
    const int* __restrict__ gcur, const int* __restrict__ pre,
    const int* __restrict__ bsum, int* __restrict__ offsets,
    int* __restrict__ esrc, int n, int e_count) {
  __shared__ int bs[NBKT];
  __shared__ int red[256];
  __shared__ int lcur[256];
  const int b = blockIdx.x, tid = threadIdx.x;
  for (int i = tid; i < NBKT; i += 256) bs[i] = bsum[i];
  __syncthreads();
  int part_ = 0;
  for (int i = tid; i < b; i += 256) part_ += bs[i];
  red[tid] = part_;
  __syncthreads();
  for (int o = 128; o; o >>= 1) {
    if (tid < o) red[tid] += red[tid + o];
    __syncthreads();
  }
  int base = red[0];
  int node = (b << 8) + tid;
  int ofs = base;
  if (node < n) {
    ofs = base + pre[node];
    offsets[node] = ofs;
  }
  lcur[tid] = ofs;
  if (b == NBKT - 1 && tid == 0) offsets[n] = e_count;
  __syncthreads();
  for (int P = 0; P < 8; ++P) {
    int cn = gcur[(P * NBKT + b) * 16];
    const unsigned* seg = part + (size_t)(P * NBKT + b) * CAP;
    for (int i = tid; i < cn; i += 256) {
      unsigned e = seg[i];
      int slot = atomicAdd(&lcur[e & 255], 1);
      esrc[slot] = (int)(e >> 8);
    }
  }
}

// ------- MFMA GEMM: B in LDS (staged once), C via LDS bounce, alpha via MFMA ----
template <int K, int N, typename AT>
__global__ __launch_bounds__(256) void gemm_mfma(const AT* __restrict__ A,
    const _Float16* __restrict__ Bh, const _Float16* __restrict__ VA,
    _Float16* __restrict__ C, int M, float* __restrict__ asrc, float* __restrict__ adst) {
  constexpr int H = N / 64;
  constexpr int KS = K / 32, NT = N / 16;
  constexpr int BM = 400, NG = 7;
  constexpr int CP = N + 8;
  __shared__ _Float16 Bs[N * K];
  __shared__ _Float16 VAs[16 * K];
  __shared__ _Float16 Cs[64 * CP];
  const int tid = threadIdx.x;
  const int lane = tid & 63, wid = tid >> 6;
  const int lr = lane & 15, lk = (lane >> 4) * 8;
  const int bm = blockIdx.x * BM;

  for (int i = tid * 8; i < N * K; i += 2048) {
    int row = i / K, k = i & (K - 1);
    f16x8 v = *(const f16x8*)&Bh[i];
    *(f16x8*)&Bs[(row * K + k) ^ ((row & 7) << 3)] = v;
  }
  for (int i = tid * 8; i < 16 * K; i += 2048) {
    int row = i / K, k = i & (K - 1);
    f16x8 v = *(const f16x8*)&VA[i];
    *(f16x8*)&VAs[(row * K + k) ^ ((row & 7) << 3)] = v;
  }
  __syncthreads();

  auto loadA = [&](int g, f16x8* areg) {
    int rlocal = g * 64 + wid * 16 + lr;
    int row = bm + rlocal;
    if (rlocal < BM && row < M) {
      const AT* arow = A + (size_t)row * K;
#pragma unroll
      for (int ks = 0; ks < KS; ++ks) {
        if constexpr (std::is_same<AT, float>::value) {
          float4 v0 = *(const float4*)&arow[ks * 32 + lk];
          float4 v1 = *(const float4*)&arow[ks * 32 + lk + 4];
          f16x8 t;
          t[0] = (_Float16)v0.x; t[1] = (_Float16)v0.y; t[2] = (_Float16)v0.z; t[3] = (_Float16)v0.w;
          t[4] = (_Float16)v1.x; t[5] = (_Float16)v1.y; t[6] = (_Float16)v1.z; t[7] = (_Float16)v1.w;
          areg[ks] = t;
        } else {
          areg[ks] = *(const f16x8*)&arow[ks * 32 + lk];
        }
      }
    } else {
#pragma unroll
      for (int ks = 0; ks < KS; ++ks) areg[ks] = (f16x8){};
    }
  };

  f16x8 a[KS], an[KS];
  loadA(0, a);
  const int rl0 = wid * 16 + (lane >> 4) * 4;

  for (int g = 0; g < NG; ++g) {
    if (g + 1 < NG) loadA(g + 1, an);

    f32x4 accv = (f32x4){0.f, 0.f, 0.f, 0.f};
#pragma unroll
    for (int ks = 0; ks < KS; ++ks) {
      f16x8 bv = *(const f16x8*)&VAs[(lr * K + ks * 32 + lk) ^ ((lr & 7) << 3)];
      accv = __builtin_amdgcn_mfma_f32_16x16x32_f16(a[ks], bv, accv, 0, 0, 0);
    }

    f32x4 acc[NT];
#pragma unroll
    for (int nt = 0; nt < NT; ++nt) acc[nt] = (f32x4){0.f, 0.f, 0.f, 0.f};
#pragma unroll
    for (int nt = 0; nt < NT; ++nt) {
      int brow = nt * 16 + lr;
#pragma unroll
      for (int ks = 0; ks < KS; ++ks) {
        f16x8 b = *(const f16x8*)&Bs[(brow * K + ks * 32 + lk) ^ ((brow & 7) << 3)];
        acc[nt] = __builtin_amdgcn_mfma_f32_16x16x32_f16(a[ks], b, acc[nt], 0, 0, 0);
      }
    }

#pragma unroll
    for (int r = 0; r < 4; ++r) {
      int rl = rl0 + r;
#pragma unroll
      for (int nt = 0; nt < NT; ++nt) Cs[rl * CP + nt * 16 + lr] = (_Float16)acc[nt][r];
      int rlocal = g * 64 + rl;
      int row = bm + rlocal;
      if (rlocal < BM && row < M) {
        if (lr < H) asrc[row * H + lr] = accv[r];
        else if (lr < 2 * H) adst[row * H + lr - H] = accv[r];
      }
    }
    __syncthreads();

    int rmax = min(64, min(BM - g * 64, M - (bm + g * 64)));
    if (rmax > 0) {
      int nch = rmax * (N / 8);
      for (int q = tid; q < nch; q += 256) {
        int row = q / (N / 8), c8 = q % (N / 8);
        f16x8 v = *(const f16x8*)&Cs[row * CP + c8 * 8];
        *(f16x8*)&C[(size_t)(bm + g * 64 + row) * N + c8 * 8] = v;
      }
    }
    __syncthreads();
#pragma unroll
    for (int ks = 0; ks < KS; ++ks) a[ks] = an[ks];
  }
}

// ------------- layer-1 aggregation: one WAVE per node, 8-deep, high occupancy ---
__global__ __launch_bounds__(256, 8) void agg1_kernel(const _Float16* __restrict__ hmat,
    const float* __restrict__ asrc, const float* __restrict__ adst,
    const int* __restrict__ offsets, const int* __restrict__ esrc,
    const float* __restrict__ bias, _Float16* __restrict__ outv, int node0) {
  const int lane = threadIdx.x & 63, wid = threadIdx.x >> 6;
  const int node = node0 + blockIdx.x * 4 + wid;
  if (node >= NNODES) return;
  const int h = lane >> 4;
  const int start = offsets[node];
  const int end = offsets[node + 1];
  const float adn = adst[node * 4 + h];
  const _Float16* hbase = hmat + lane * 4;
  float acc[4] = {0.f, 0.f, 0.f, 0.f};
  float s = 0.f;
  int j = start;
  for (; j + 8 <= end; j += 8) {
    int sv[8];
#pragma unroll
    for (int t = 0; t < 8; ++t) sv[t] = esrc[j + t];
    f16x4 vv[8];
#pragma unroll
    for (int t = 0; t < 8; ++t) vv[t] = *(const f16x4*)&hbase[(size_t)sv[t] * 256];
    _Float16 ph[8];
#pragma unroll
    for (int t = 0; t < 8; ++t) {
      float v = asrc[sv[t] * 4 + h] + adn;
      v = (v > 0.f) ? v : 0.2f * v;
      float p = __expf(v);
      s += p;
      ph[t] = (_Float16)p;
    }
#pragma unroll
    for (int t = 0; t < 8; ++t)
#pragma unroll
      for (int k = 0; k < 4; ++k)
        acc[k] = fmaf((float)vv[t][k], (float)ph[t], acc[k]);  // v_fma_mix_f32
  }
  for (; j < end; ++j) {
    int sv = esrc[j];
    f16x4 vv = *(const f16x4*)&hbase[(size_t)sv * 256];
    float v = asrc[sv * 4 + h] + adn;
    v = (v > 0.f) ? v : 0.2f * v;
    float p = __expf(v);
    s += p;
    _Float16 phs = (_Float16)p;
#pragma unroll
    for (int k = 0; k < 4; ++k) acc[k] = fmaf((float)vv[k], (float)phs, acc[k]);
  }
  float inv = 1.f / (s + 1e-16f);
  f16x4 ho;
#pragma unroll
  for (int k = 0; k < 4; ++k)
    ho[k] = (_Float16)fmaxf(fmaf(acc[k], inv, bias[lane * 4 + k]), 0.f);
  *(f16x4*)&outv[(size_t)node * 256 + lane * 4] = ho;
}

// ------------- layer-2 aggregation: node per 16-lane group, 8-deep, f16 out -----
__global__ __launch_bounds__(256, 8) void agg2_kernel(const _Float16* __restrict__ hmat,
    const float* __restrict__ asrc, const float* __restrict__ adst,
    const int* __restrict__ offsets, const int* __restrict__ esrc,
    const float* __restrict__ bias, _Float16* __restrict__ outv) {
  const int lane = threadIdx.x & 63, wid = threadIdx.x >> 6;
  const int g = lane >> 4, q = lane & 15;
  const int node = blockIdx.x * 16 + wid * 4 + g;
  if (node >= NNODES) return;
  const int start = offsets[node];
  const int end = offsets[node + 1];
  const float adn = adst[node];
  const _Float16* hbase = hmat + q * 4;
  float acc[4] = {0.f, 0.f, 0.f, 0.f};
  float s = 0.f;
  int j = start;
  for (; j + 8 <= end; j += 8) {
    int sv[8];
#pragma unroll
    for (int t = 0; t < 8; ++t) sv[t] = esrc[j + t];
    f16x4 v[8];
#pragma unroll
    for (int t = 0; t < 8; ++t) v[t] = *(const f16x4*)&hbase[(size_t)sv[t] * 64];
#pragma unroll
    for (int t = 0; t < 8; ++t) {
      float x = asrc[sv[t]] + adn;
      x = (x > 0.f) ? x : 0.2f * x;
      float p = __expf(x);
      s += p;
      _Float16 phs = (_Float16)p;
#pragma unroll
      for (int k = 0; k < 4; ++k) acc[k] = fmaf((float)v[t][k], (float)phs, acc[k]);
    }
  }
  for (; j < end; ++j) {
    int sv = esrc[j];
    f16x4 v = *(const f16x4*)&hbase[(size_t)sv * 64];
    float x = asrc[sv] + adn;
    x = (x > 0.f) ? x : 0.2f * x;
    float p = __expf(x);
    s += p;
    _Float16 phs = (_Float16)p;
#pragma unroll
    for (int k = 0; k < 4; ++k) acc[k] = fmaf((float)v[k], (float)phs, acc[k]);
  }
  float inv = 1.f / (s + 1e-16f);
  f16x4 ho;
#pragma unroll
  for (int k = 0; k < 4; ++k)
    ho[k] = (_Float16)fmaxf(fmaf(acc[k], inv, bias[q * 4 + k]), 0.f);
  *(f16x4*)&outv[(size_t)node * 64 + q * 4] = ho;
}

// ---------------- fused global mean pool (f16 input, fp32 accumulate) -----------
__global__ __launch_bounds__(256) void pool_kernel(const _Float16* __restrict__ g2,
    const int* __restrict__ batch, float* __restrict__ out, int n) {
  const int gid = blockIdx.x;
  const int lane = threadIdx.x & 63, w = threadIdx.x >> 6;
  int lo = 0, hi = n;
  while (lo < hi) { int mid = (lo + hi) >> 1; if (batch[mid] < gid) lo = mid + 1; else hi = mid; }
  int lb = lo;
  hi = n;
  while (lo < hi) { int mid = (lo + hi) >> 1; if (batch[mid] < gid + 1) lo = mid + 1; else hi = mid; }
  int ub = lo;
  float acc = 0.f;
  for (int i = lb + w; i < ub; i += 4) acc += (float)g2[(size_t)i * 64 + lane];
  __shared__ float red[4][64];
  red[w][lane] = acc;
  __syncthreads();
  if (threadIdx.x < 64) {
    float sum = (red[0][lane] + red[1][lane]) + (red[2][lane] + red[3][lane]);
    float cnt = fmaxf((float)(ub - lb), 1.f);
    out[gid * 64 + lane] = sum / cnt;
  }
}

// ---------------- launcher ----------------
extern "C" void kernel_launch(void* const* d_in, const int* in_sizes, int n_in,
                              void* d_out, int out_size, void* d_ws, size_t ws_size,
                              hipStream_t stream) {
  const float* x      = (const float*)d_in[0];
  const float* w1     = (const float*)d_in[1];
  const float* a_src1 = (const float*)d_in[2];
  const float* a_dst1 = (const float*)d_in[3];
  const float* b1     = (const float*)d_in[4];
  const float* w2     = (const float*)d_in[5];
  const float* a_src2 = (const float*)d_in[6];
  const float* a_dst2 = (const float*)d_in[7];
  const float* b2     = (const float*)d_in[8];
  const int*   src    = (const int*)d_in[9];
  const int*   dst    = src + NEDGES;
  const int*   batch  = (const int*)d_in[10];
  float* out = (float*)d_out;

  const int N = NNODES, E = NEDGES;

  char* wsb = (char*)d_ws;
  size_t off = 0;
  auto alloc = [&](size_t bytes) {
    void* p = wsb + off;
    off = (off + bytes + 255) & ~(size_t)255;
    return p;
  };
  _Float16* h1h = (_Float16*)alloc((size_t)N * 256 * 2);
  _Float16* g1h = (_Float16*)alloc((size_t)N * 256 * 2);
  _Float16* h2h = (_Float16*)alloc((size_t)N * 64 * 2);
  _Float16* g2h = (_Float16*)alloc((size_t)N * 64 * 2);
  float* as1    = (float*)alloc((size_t)N * 4 * 4);
  float* ad1    = (float*)alloc((size_t)N * 4 * 4);
  float* as2    = (float*)alloc((size_t)N * 4);
  float* ad2    = (float*)alloc((size_t)N * 4);
  int* pre      = (int*)alloc((size_t)N * 4);
  int* bsum     = (int*)alloc((size_t)NBKT * 4);
  int* offsets  = (int*)alloc((size_t)(N + 1) * 4);
  int* esrc     = (int*)alloc((size_t)E * 4);
  unsigned* part= (unsigned*)alloc((size_t)8 * NBKT * CAP * 4);
  int* gcur     = (int*)alloc((size_t)8 * NBKT * 16 * 4);
  _Float16* w1h = (_Float16*)alloc((size_t)256 * 128 * 2);
  _Float16* w2h = (_Float16*)alloc((size_t)64 * 256 * 2);
  _Float16* va1 = (_Float16*)alloc((size_t)16 * 128 * 2);
  _Float16* va2 = (_Float16*)alloc((size_t)16 * 256 * 2);

  // ---- front: convert+GEMV || edge partition ----
  hipMemsetAsync(gcur, 0, (size_t)8 * NBKT * 16 * 4, stream);
  front1<<<202 + (E + EPB - 1) / EPB, 256, 0, stream>>>(
      w1, w2, a_src1, a_dst1, a_src2, a_dst2, w1h, w2h, va1, va2,
      src, dst, part, gcur, E);

  // ---- CSR build ----
  bucketB1p<<<NBKT, 256, 0, stream>>>(part, gcur, pre, bsum, N);
  bucketB2<<<NBKT, 256, 0, stream>>>(part, gcur, pre, bsum, offsets, esrc, N, E);

  // ---- layer 1 ----
  gemm_mfma<128, 256, float><<<250, 256, 0, stream>>>(
      x, w1h, va1, h1h, N, as1, ad1);
  agg1_kernel<<<12500, 256, 0, stream>>>(h1h, as1, ad1, offsets, esrc, b1, g1h, 0);
  agg1_kernel<<<12500, 256, 0, stream>>>(h1h, as1, ad1, offsets, esrc, b1, g1h, 50000);

  // ---- layer 2 ----
  gemm_mfma<256, 64, _Float16><<<250, 256, 0, stream>>>(
      g1h, w2h, va2, h2h, N, as2, ad2);
  agg2_kernel<<<(N + 15) / 16, 256, 0, stream>>>(h2h, as2, ad2, offsets, esrc, b2, g2h);

  // ---- pool ----
  pool_kernel<<<NGRAPH, 256, 0, stream>>>(g2h, batch, out, N);
}

// Round 17
// 351.859 us; speedup vs baseline: 1.0016x; 1.0016x over previous
//
#include <hip/hip_runtime.h>
#include <math.h>
#include <type_traits>

#define NNODES 100000
#define NEDGES 1600000
#define NGRAPH 128
#define NBKT 391          // dst buckets of 256 nodes
#define CAP 1536          // per (partition,bucket) capacity
#define EPB 2048          // edges per bucketA block

typedef _Float16 f16x4 __attribute__((ext_vector_type(4)));
typedef _Float16 f16x8 __attribute__((ext_vector_type(8)));
typedef float f32x4 __attribute__((ext_vector_type(4)));

// ---- front1: weight convert + alpha GEMV (blocks 0-201)  ||  bucketA (202+) ----
__global__ __launch_bounds__(256) void front1(
    const float* __restrict__ w1, const float* __restrict__ w2,
    const float* __restrict__ as1c, const float* __restrict__ ad1c,
    const float* __restrict__ as2c, const float* __restrict__ ad2c,
    _Float16* __restrict__ w1h, _Float16* __restrict__ w2h,
    _Float16* __restrict__ va1, _Float16* __restrict__ va2,
    const int* __restrict__ srcv, const int* __restrict__ dstv,
    unsigned* __restrict__ part, int* __restrict__ gcur, int e_count) {
  __shared__ int hist[NBKT];
  __shared__ int base_[NBKT];
  __shared__ int lofs[NBKT];
  const int tid = threadIdx.x;
  if (blockIdx.x < 202) {
    const int b = blockIdx.x;
    if (b < 8) {
      if (tid < 128) {
        int h = b & 3;
        const float* coef = (b >= 4) ? ad1c : as1c;
        float s = 0.f;
        for (int c = 0; c < 64; ++c)
          s = fmaf(w1[(size_t)(h * 64 + c) * 128 + tid], coef[h * 64 + c], s);
        va1[b * 128 + tid] = (_Float16)s;
        va1[(b + 8) * 128 + tid] = (_Float16)0.f;
      }
    } else if (b < 10) {
      int r = b - 8;
      const float* coef = r ? ad2c : as2c;
      float s = 0.f;
      for (int c = 0; c < 64; ++c) s = fmaf(w2[(size_t)c * 256 + tid], coef[c], s);
      va2[r * 256 + tid] = (_Float16)s;
      for (int z = 2 + r * 7; z < 9 + r * 7; ++z) va2[z * 256 + tid] = (_Float16)0.f;
    } else if (b < 138) {
      int i = (b - 10) * 256 + tid;
      w1h[i] = (_Float16)w1[i];
    } else {
      int i = (b - 138) * 256 + tid;
      w2h[i] = (_Float16)w2[i];
    }
    return;
  }
  const int ab = blockIdx.x - 202;
  const int P = ab & 7;
  for (int i = tid; i < NBKT; i += 256) { hist[i] = 0; lofs[i] = 0; }
  __syncthreads();
  const int e0 = ab * EPB;
  const int e1 = min(e0 + EPB, e_count);
  for (int e = e0 + tid; e < e1; e += 256) atomicAdd(&hist[dstv[e] >> 8], 1);
  __syncthreads();
  for (int i = tid; i < NBKT; i += 256) {
    int c = hist[i];
    base_[i] = c ? atomicAdd(&gcur[(P * NBKT + i) * 16], c) : 0;
  }
  __syncthreads();
  for (int e = e0 + tid; e < e1; e += 256) {
    int d = dstv[e];
    int b = d >> 8;
    int l = atomicAdd(&lofs[b], 1);
    part[(size_t)(P * NBKT + b) * CAP + base_[b] + l] =
        ((unsigned)srcv[e] << 8) | (unsigned)(d & 255);
  }
}

// ---- bucketB1p: per-node degree count + in-bucket exclusive prefix + bucket sum -
__global__ __launch_bounds__(256) void bucketB1p(const unsigned* __restrict__ part,
    const int* __restrict__ gcur, int* __restrict__ pre, int* __restrict__ bsum, int n) {
  __shared__ int cnt[256];
  __shared__ int sc[256];
  const int b = blockIdx.x, tid = threadIdx.x;
  cnt[tid] = 0;
  __syncthreads();
  for (int P = 0; P < 8; ++P) {
    int cn = gcur[(P * NBKT + b) * 16];
    const unsigned* seg = part + (size_t)(P * NBKT + b) * CAP;
    for (int i = tid; i < cn; i += 256) atomicAdd(&cnt[seg[i] & 255], 1);
  }
  __syncthreads();
  int own = cnt[tid];
  sc[tid] = own;
  __syncthreads();
  for (int o = 1; o < 256; o <<= 1) {
    int t = (tid >= o) ? sc[tid - o] : 0;
    __syncthreads();
    sc[tid] += t;
    __syncthreads();
  }
  int node = (b << 8) + tid;
  if (node < n) pre[node] = sc[tid] - own;
  if (tid == 255) bsum[b] = sc[255];
}

// ---- bucketB2: derive offsets (cross-bucket base from bsum) + place esrc --------
__global__ __launch_bounds__(256) void bucketB2(const unsigned* __restrict__ part,
    const int* __restrict__ gcur, const int* __restrict__ pre,
    const int* __restrict__ bsum, int* __restrict__ offsets,
    int* __restrict__ esrc, int n, int e_count) {
  __shared__ int bs[NBKT];
  __shared__ int red[256];
  __shared__ int lcur[256];
  const int b = blockIdx.x, tid = threadIdx.x;
  for (int i = tid; i < NBKT; i += 256) bs[i] = bsum[i];
  __syncthreads();
  int part_ = 0;
  for (int i = tid; i < b; i += 256) part_ += bs[i];
  red[tid] = part_;
  __syncthreads();
  for (int o = 128; o; o >>= 1) {
    if (tid < o) red[tid] += red[tid + o];
    __syncthreads();
  }
  int base = red[0];
  int node = (b << 8) + tid;
  int ofs = base;
  if (node < n) {
    ofs = base + pre[node];
    offsets[node] = ofs;
  }
  lcur[tid] = ofs;
  if (b == NBKT - 1 && tid == 0) offsets[n] = e_count;
  __syncthreads();
  for (int P = 0; P < 8; ++P) {
    int cn = gcur[(P * NBKT + b) * 16];
    const unsigned* seg = part + (size_t)(P * NBKT + b) * CAP;
    for (int i = tid; i < cn; i += 256) {
      unsigned e = seg[i];
      int slot = atomicAdd(&lcur[e & 255], 1);
      esrc[slot] = (int)(e >> 8);
    }
  }
}

// ------- MFMA GEMM: B in LDS, small 16-row C bounce (2 blocks/CU), alpha MFMA ---
template <int K, int N, typename AT>
__global__ __launch_bounds__(256) void gemm_mfma(const AT* __restrict__ A,
    const _Float16* __restrict__ Bh, const _Float16* __restrict__ VA,
    _Float16* __restrict__ C, int M, float* __restrict__ asrc, float* __restrict__ adst) {
  constexpr int H = N / 64;
  constexpr int KS = K / 32, NT = N / 16;
  constexpr int BM = 400, NG = 7;
  constexpr int CP = N + 8;
  __shared__ _Float16 Bs[N * K];
  __shared__ _Float16 VAs[16 * K];
  __shared__ _Float16 Cs[16 * CP];     // 16-row bounce tile
  const int tid = threadIdx.x;
  const int lane = tid & 63, wid = tid >> 6;
  const int lr = lane & 15, lk = (lane >> 4) * 8;
  const int bm = blockIdx.x * BM;

  for (int i = tid * 8; i < N * K; i += 2048) {
    int row = i / K, k = i & (K - 1);
    f16x8 v = *(const f16x8*)&Bh[i];
    *(f16x8*)&Bs[(row * K + k) ^ ((row & 7) << 3)] = v;
  }
  for (int i = tid * 8; i < 16 * K; i += 2048) {
    int row = i / K, k = i & (K - 1);
    f16x8 v = *(const f16x8*)&VA[i];
    *(f16x8*)&VAs[(row * K + k) ^ ((row & 7) << 3)] = v;
  }
  __syncthreads();

  auto loadA = [&](int g, f16x8* areg) {
    int rlocal = g * 64 + wid * 16 + lr;
    int row = bm + rlocal;
    if (rlocal < BM && row < M) {
      const AT* arow = A + (size_t)row * K;
#pragma unroll
      for (int ks = 0; ks < KS; ++ks) {
        if constexpr (std::is_same<AT, float>::value) {
          float4 v0 = *(const float4*)&arow[ks * 32 + lk];
          float4 v1 = *(const float4*)&arow[ks * 32 + lk + 4];
          f16x8 t;
          t[0] = (_Float16)v0.x; t[1] = (_Float16)v0.y; t[2] = (_Float16)v0.z; t[3] = (_Float16)v0.w;
          t[4] = (_Float16)v1.x; t[5] = (_Float16)v1.y; t[6] = (_Float16)v1.z; t[7] = (_Float16)v1.w;
          areg[ks] = t;
        } else {
          areg[ks] = *(const f16x8*)&arow[ks * 32 + lk];
        }
      }
    } else {
#pragma unroll
      for (int ks = 0; ks < KS; ++ks) areg[ks] = (f16x8){};
    }
  };

  f16x8 a[KS], an[KS];
  loadA(0, a);

  for (int g = 0; g < NG; ++g) {
    if (g + 1 < NG) loadA(g + 1, an);

    // alpha logits (cols 0..2H-1 = {src heads, dst heads})
    f32x4 accv = (f32x4){0.f, 0.f, 0.f, 0.f};
#pragma unroll
    for (int ks = 0; ks < KS; ++ks) {
      f16x8 bv = *(const f16x8*)&VAs[(lr * K + ks * 32 + lk) ^ ((lr & 7) << 3)];
      accv = __builtin_amdgcn_mfma_f32_16x16x32_f16(a[ks], bv, accv, 0, 0, 0);
    }

    f32x4 acc[NT];
#pragma unroll
    for (int nt = 0; nt < NT; ++nt) acc[nt] = (f32x4){0.f, 0.f, 0.f, 0.f};
#pragma unroll
    for (int nt = 0; nt < NT; ++nt) {
      int brow = nt * 16 + lr;
#pragma unroll
      for (int ks = 0; ks < KS; ++ks) {
        f16x8 b = *(const f16x8*)&Bs[(brow * K + ks * 32 + lk) ^ ((brow & 7) << 3)];
        acc[nt] = __builtin_amdgcn_mfma_f32_16x16x32_f16(a[ks], b, acc[nt], 0, 0, 0);
      }
    }

    // alpha direct to global
#pragma unroll
    for (int r = 0; r < 4; ++r) {
      int rlocal = g * 64 + wid * 16 + (lane >> 4) * 4 + r;
      int row = bm + rlocal;
      if (rlocal < BM && row < M) {
        if (lr < H) asrc[row * H + lr] = accv[r];
        else if (lr < 2 * H) adst[row * H + lr - H] = accv[r];
      }
    }

    // C through 16-row LDS bounce, one wave-owned quarter at a time
    for (int q = 0; q < 4; ++q) {
      int qrows = min(16, BM - g * 64 - q * 16);
      if (qrows <= 0) break;
      if (wid == q) {
#pragma unroll
        for (int r = 0; r < 4; ++r) {
          int rl = (lane >> 4) * 4 + r;
#pragma unroll
          for (int nt = 0; nt < NT; ++nt) Cs[rl * CP + nt * 16 + lr] = (_Float16)acc[nt][r];
        }
      }
      __syncthreads();
      int rbase = bm + g * 64 + q * 16;
      int rmax = min(qrows, M - rbase);
      if (rmax > 0) {
        int nch = rmax * (N / 8);
        for (int idx = tid; idx < nch; idx += 256) {
          int row = idx / (N / 8), c8 = idx % (N / 8);
          f16x8 v = *(const f16x8*)&Cs[row * CP + c8 * 8];
          *(f16x8*)&C[(size_t)(rbase + row) * N + c8 * 8] = v;
        }
      }
      __syncthreads();
    }
#pragma unroll
    for (int ks = 0; ks < KS; ++ks) a[ks] = an[ks];
  }
}

// ------------- layer-1 aggregation: one WAVE per node, 8-deep gather pipeline ---
__global__ __launch_bounds__(256) void agg1_kernel(const _Float16* __restrict__ hmat,
    const float* __restrict__ asrc, const float* __restrict__ adst,
    const int* __restrict__ offsets, const int* __restrict__ esrc,
    const float* __restrict__ bias, _Float16* __restrict__ outv) {
  const int lane = threadIdx.x & 63, wid = threadIdx.x >> 6;
  const int node = blockIdx.x * 4 + wid;
  if (node >= NNODES) return;
  const int h = lane >> 4;
  const int start = offsets[node];
  const int end = offsets[node + 1];
  const float adn = adst[node * 4 + h];
  const _Float16* hbase = hmat + lane * 4;
  float acc[4] = {0.f, 0.f, 0.f, 0.f};
  float s = 0.f;
  int j = start;
  for (; j + 8 <= end; j += 8) {
    int sv[8];
#pragma unroll
    for (int t = 0; t < 8; ++t) sv[t] = esrc[j + t];
    f16x4 vv[8];
#pragma unroll
    for (int t = 0; t < 8; ++t) vv[t] = *(const f16x4*)&hbase[(size_t)sv[t] * 256];
    _Float16 ph[8];
#pragma unroll
    for (int t = 0; t < 8; ++t) {
      float v = asrc[sv[t] * 4 + h] + adn;
      v = (v > 0.f) ? v : 0.2f * v;
      float p = __expf(v);
      s += p;
      ph[t] = (_Float16)p;
    }
#pragma unroll
    for (int t = 0; t < 8; ++t)
#pragma unroll
      for (int k = 0; k < 4; ++k)
        acc[k] = fmaf((float)vv[t][k], (float)ph[t], acc[k]);  // v_fma_mix_f32
  }
  for (; j < end; ++j) {
    int sv = esrc[j];
    f16x4 vv = *(const f16x4*)&hbase[(size_t)sv * 256];
    float v = asrc[sv * 4 + h] + adn;
    v = (v > 0.f) ? v : 0.2f * v;
    float p = __expf(v);
    s += p;
    _Float16 phs = (_Float16)p;
#pragma unroll
    for (int k = 0; k < 4; ++k) acc[k] = fmaf((float)vv[k], (float)phs, acc[k]);
  }
  float inv = 1.f / (s + 1e-16f);
  f16x4 ho;
#pragma unroll
  for (int k = 0; k < 4; ++k)
    ho[k] = (_Float16)fmaxf(fmaf(acc[k], inv, bias[lane * 4 + k]), 0.f);
  *(f16x4*)&outv[(size_t)node * 256 + lane * 4] = ho;
}

// ------------- layer-2 aggregation: node per 16-lane group, 8-deep, f16 out -----
__global__ __launch_bounds__(256) void agg2_kernel(const _Float16* __restrict__ hmat,
    const float* __restrict__ asrc, const float* __restrict__ adst,
    const int* __restrict__ offsets, const int* __restrict__ esrc,
    const float* __restrict__ bias, _Float16* __restrict__ outv) {
  const int lane = threadIdx.x & 63, wid = threadIdx.x >> 6;
  const int g = lane >> 4, q = lane & 15;
  const int node = blockIdx.x * 16 + wid * 4 + g;
  if (node >= NNODES) return;
  const int start = offsets[node];
  const int end = offsets[node + 1];
  const float adn = adst[node];
  const _Float16* hbase = hmat + q * 4;
  float acc[4] = {0.f, 0.f, 0.f, 0.f};
  float s = 0.f;
  int j = start;
  for (; j + 8 <= end; j += 8) {
    int sv[8];
#pragma unroll
    for (int t = 0; t < 8; ++t) sv[t] = esrc[j + t];
    f16x4 v[8];
#pragma unroll
    for (int t = 0; t < 8; ++t) v[t] = *(const f16x4*)&hbase[(size_t)sv[t] * 64];
#pragma unroll
    for (int t = 0; t < 8; ++t) {
      float x = asrc[sv[t]] + adn;
      x = (x > 0.f) ? x : 0.2f * x;
      float p = __expf(x);
      s += p;
      _Float16 phs = (_Float16)p;
#pragma unroll
      for (int k = 0; k < 4; ++k) acc[k] = fmaf((float)v[t][k], (float)phs, acc[k]);
    }
  }
  for (; j < end; ++j) {
    int sv = esrc[j];
    f16x4 v = *(const f16x4*)&hbase[(size_t)sv * 64];
    float x = asrc[sv] + adn;
    x = (x > 0.f) ? x : 0.2f * x;
    float p = __expf(x);
    s += p;
    _Float16 phs = (_Float16)p;
#pragma unroll
    for (int k = 0; k < 4; ++k) acc[k] = fmaf((float)v[k], (float)phs, acc[k]);
  }
  float inv = 1.f / (s + 1e-16f);
  f16x4 ho;
#pragma unroll
  for (int k = 0; k < 4; ++k)
    ho[k] = (_Float16)fmaxf(fmaf(acc[k], inv, bias[q * 4 + k]), 0.f);
  *(f16x4*)&outv[(size_t)node * 64 + q * 4] = ho;
}

// ---------------- fused global mean pool (f16 input, fp32 accumulate) -----------
__global__ __launch_bounds__(256) void pool_kernel(const _Float16* __restrict__ g2,
    const int* __restrict__ batch, float* __restrict__ out, int n) {
  const int gid = blockIdx.x;
  const int lane = threadIdx.x & 63, w = threadIdx.x >> 6;
  int lo = 0, hi = n;
  while (lo < hi) { int mid = (lo + hi) >> 1; if (batch[mid] < gid) lo = mid + 1; else hi = mid; }
  int lb = lo;
  hi = n;
  while (lo < hi) { int mid = (lo + hi) >> 1; if (batch[mid] < gid + 1) lo = mid + 1; else hi = mid; }
  int ub = lo;
  float acc = 0.f;
  for (int i = lb + w; i < ub; i += 4) acc += (float)g2[(size_t)i * 64 + lane];
  __shared__ float red[4][64];
  red[w][lane] = acc;
  __syncthreads();
  if (threadIdx.x < 64) {
    float sum = (red[0][lane] + red[1][lane]) + (red[2][lane] + red[3][lane]);
    float cnt = fmaxf((float)(ub - lb), 1.f);
    out[gid * 64 + lane] = sum / cnt;
  }
}

// ---------------- launcher ----------------
extern "C" void kernel_launch(void* const* d_in, const int* in_sizes, int n_in,
                              void* d_out, int out_size, void* d_ws, size_t ws_size,
                              hipStream_t stream) {
  const float* x      = (const float*)d_in[0];
  const float* w1     = (const float*)d_in[1];
  const float* a_src1 = (const float*)d_in[2];
  const float* a_dst1 = (const float*)d_in[3];
  const float* b1     = (const float*)d_in[4];
  const float* w2     = (const float*)d_in[5];
  const float* a_src2 = (const float*)d_in[6];
  const float* a_dst2 = (const float*)d_in[7];
  const float* b2     = (const float*)d_in[8];
  const int*   src    = (const int*)d_in[9];
  const int*   dst    = src + NEDGES;
  const int*   batch  = (const int*)d_in[10];
  float* out = (float*)d_out;

  const int N = NNODES, E = NEDGES;

  char* wsb = (char*)d_ws;
  size_t off = 0;
  auto alloc = [&](size_t bytes) {
    void* p = wsb + off;
    off = (off + bytes + 255) & ~(size_t)255;
    return p;
  };
  _Float16* h1h = (_Float16*)alloc((size_t)N * 256 * 2);
  _Float16* g1h = (_Float16*)alloc((size_t)N * 256 * 2);
  _Float16* h2h = (_Float16*)alloc((size_t)N * 64 * 2);
  _Float16* g2h = (_Float16*)alloc((size_t)N * 64 * 2);
  float* as1    = (float*)alloc((size_t)N * 4 * 4);
  float* ad1    = (float*)alloc((size_t)N * 4 * 4);
  float* as2    = (float*)alloc((size_t)N * 4);
  float* ad2    = (float*)alloc((size_t)N * 4);
  int* pre      = (int*)alloc((size_t)N * 4);
  int* bsum     = (int*)alloc((size_t)NBKT * 4);
  int* offsets  = (int*)alloc((size_t)(N + 1) * 4);
  int* esrc     = (int*)alloc((size_t)E * 4);
  unsigned* part= (unsigned*)alloc((size_t)8 * NBKT * CAP * 4);
  int* gcur     = (int*)alloc((size_t)8 * NBKT * 16 * 4);
  _Float16* w1h = (_Float16*)alloc((size_t)256 * 128 * 2);
  _Float16* w2h = (_Float16*)alloc((size_t)64 * 256 * 2);
  _Float16* va1 = (_Float16*)alloc((size_t)16 * 128 * 2);
  _Float16* va2 = (_Float16*)alloc((size_t)16 * 256 * 2);

  // ---- front: convert+GEMV || edge partition ----
  hipMemsetAsync(gcur, 0, (size_t)8 * NBKT * 16 * 4, stream);
  front1<<<202 + (E + EPB - 1) / EPB, 256, 0, stream>>>(
      w1, w2, a_src1, a_dst1, a_src2, a_dst2, w1h, w2h, va1, va2,
      src, dst, part, gcur, E);

  // ---- CSR build ----
  bucketB1p<<<NBKT, 256, 0, stream>>>(part, gcur, pre, bsum, N);
  bucketB2<<<NBKT, 256, 0, stream>>>(part, gcur, pre, bsum, offsets, esrc, N, E);

  // ---- layer 1 ----
  gemm_mfma<128, 256, float><<<250, 256, 0, stream>>>(
      x, w1h, va1, h1h, N, as1, ad1);
  agg1_kernel<<<(N + 3) / 4, 256, 0, stream>>>(h1h, as1, ad1, offsets, esrc, b1, g1h);

  // ---- layer 2 ----
  gemm_mfma<256, 64, _Float16><<<250, 256, 0, stream>>>(
      g1h, w2h, va2, h2h, N, as2, ad2);
  agg2_kernel<<<(N + 15) / 16, 256, 0, stream>>>(h2h, as2, ad2, offsets, esrc, b2, g2h);

  // ---- pool ----
  pool_kernel<<<NGRAPH, 256, 0, stream>>>(g2h, batch, out, N);
}

// Round 18
// 344.506 us; speedup vs baseline: 1.0230x; 1.0213x over previous
//
#include <hip/hip_runtime.h>
#include <math.h>
#include <type_traits>

#define NNODES 100000
#define NEDGES 1600000
#define NGRAPH 128
#define NBKT 391          // dst buckets of 256 nodes
#define CAP 1536          // per (partition,bucket) capacity
#define EPB 2048          // edges per bucketA block

typedef _Float16 f16x4 __attribute__((ext_vector_type(4)));
typedef _Float16 f16x8 __attribute__((ext_vector_type(8)));
typedef float f32x4 __attribute__((ext_vector_type(4)));

// ---- front1: weight convert + alpha GEMV (blocks 0-201)  ||  bucketA (202+) ----
__global__ __launch_bounds__(256) void front1(
    const float* __restrict__ w1, const float* __restrict__ w2,
    const float* __restrict__ as1c, const float* __restrict__ ad1c,
    const float* __restrict__ as2c, const float* __restrict__ ad2c,
    _Float16* __restrict__ w1h, _Float16* __restrict__ w2h,
    _Float16* __restrict__ va1, _Float16* __restrict__ va2,
    const int* __restrict__ srcv, const int* __restrict__ dstv,
    unsigned* __restrict__ part, int* __restrict__ gcur, int e_count) {
  __shared__ int hist[NBKT];
  __shared__ int base_[NBKT];
  __shared__ int lofs[NBKT];
  const int tid = threadIdx.x;
  if (blockIdx.x < 202) {
    const int b = blockIdx.x;
    if (b < 8) {
      if (tid < 128) {
        int h = b & 3;
        const float* coef = (b >= 4) ? ad1c : as1c;
        float s = 0.f;
        for (int c = 0; c < 64; ++c)
          s = fmaf(w1[(size_t)(h * 64 + c) * 128 + tid], coef[h * 64 + c], s);
        va1[b * 128 + tid] = (_Float16)s;
        va1[(b + 8) * 128 + tid] = (_Float16)0.f;
      }
    } else if (b < 10) {
      int r = b - 8;
      const float* coef = r ? ad2c : as2c;
      float s = 0.f;
      for (int c = 0; c < 64; ++c) s = fmaf(w2[(size_t)c * 256 + tid], coef[c], s);
      va2[r * 256 + tid] = (_Float16)s;
      for (int z = 2 + r * 7; z < 9 + r * 7; ++z) va2[z * 256 + tid] = (_Float16)0.f;
    } else if (b < 138) {
      int i = (b - 10) * 256 + tid;
      w1h[i] = (_Float16)w1[i];
    } else {
      int i = (b - 138) * 256 + tid;
      w2h[i] = (_Float16)w2[i];
    }
    return;
  }
  const int ab = blockIdx.x - 202;
  const int P = ab & 7;
  for (int i = tid; i < NBKT; i += 256) { hist[i] = 0; lofs[i] = 0; }
  __syncthreads();
  const int e0 = ab * EPB;
  const int e1 = min(e0 + EPB, e_count);
  for (int e = e0 + tid; e < e1; e += 256) atomicAdd(&hist[dstv[e] >> 8], 1);
  __syncthreads();
  for (int i = tid; i < NBKT; i += 256) {
    int c = hist[i];
    base_[i] = c ? atomicAdd(&gcur[(P * NBKT + i) * 16], c) : 0;
  }
  __syncthreads();
  for (int e = e0 + tid; e < e1; e += 256) {
    int d = dstv[e];
    int b = d >> 8;
    int l = atomicAdd(&lofs[b], 1);
    part[(size_t)(P * NBKT + b) * CAP + base_[b] + l] =
        ((unsigned)srcv[e] << 8) | (unsigned)(d & 255);
  }
}

// ---- bucketB1p: per-node degree count + in-bucket exclusive prefix + bucket sum -
__global__ __launch_bounds__(256) void bucketB1p(const unsigned* __restrict__ part,
    const int* __restrict__ gcur, int* __restrict__ pre, int* __restrict__ bsum, int n) {
  __shared__ int cnt[256];
  __shared__ int sc[256];
  const int b = blockIdx.x, tid = threadIdx.x;
  cnt[tid] = 0;
  __syncthreads();
  for (int P = 0; P < 8; ++P) {
    int cn = gcur[(P * NBKT + b) * 16];
    const unsigned* seg = part + (size_t)(P * NBKT + b) * CAP;
    for (int i = tid; i < cn; i += 256) atomicAdd(&cnt[seg[i] & 255], 1);
  }
  __syncthreads();
  int own = cnt[tid];
  sc[tid] = own;
  __syncthreads();
  for (int o = 1; o < 256; o <<= 1) {
    int t = (tid >= o) ? sc[tid - o] : 0;
    __syncthreads();
    sc[tid] += t;
    __syncthreads();
  }
  int node = (b << 8) + tid;
  if (node < n) pre[node] = sc[tid] - own;
  if (tid == 255) bsum[b] = sc[255];
}

// ---- bucketB2: derive offsets (cross-bucket base from bsum) + place esrc --------
__global__ __launch_bounds__(256) void bucketB2(const unsigned* __restrict__ part,
    const int* __restrict__ gcur, const int* __restrict__ pre,
    const int* __restrict__ bsum, int* __restrict__ offsets,
    int* __restrict__ esrc, int n, int e_count) {
  __shared__ int bs[NBKT];
  __shared__ int red[256];
  __shared__ int lcur[256];
  const int b = blockIdx.x, tid = threadIdx.x;
  for (int i = tid; i < NBKT; i += 256) bs[i] = bsum[i];
  __syncthreads();
  int part_ = 0;
  for (int i = tid; i < b; i += 256) part_ += bs[i];
  red[tid] = part_;
  __syncthreads();
  for (int o = 128; o; o >>= 1) {
    if (tid < o) red[tid] += red[tid + o];
    __syncthreads();
  }
  int base = red[0];
  int node = (b << 8) + tid;
  int ofs = base;
  if (node < n) {
    ofs = base + pre[node];
    offsets[node] = ofs;
  }
  lcur[tid] = ofs;
  if (b == NBKT - 1 && tid == 0) offsets[n] = e_count;
  __syncthreads();
  for (int P = 0; P < 8; ++P) {
    int cn = gcur[(P * NBKT + b) * 16];
    const unsigned* seg = part + (size_t)(P * NBKT + b) * CAP;
    for (int i = tid; i < cn; i += 256) {
      unsigned e = seg[i];
      int slot = atomicAdd(&lcur[e & 255], 1);
      esrc[slot] = (int)(e >> 8);
    }
  }
}

// ------- MFMA GEMM: B in LDS (staged once), C via 64-row LDS bounce, alpha MFMA -
template <int K, int N, typename AT>
__global__ __launch_bounds__(256) void gemm_mfma(const AT* __restrict__ A,
    const _Float16* __restrict__ Bh, const _Float16* __restrict__ VA,
    _Float16* __restrict__ C, int M, float* __restrict__ asrc, float* __restrict__ adst) {
  constexpr int H = N / 64;
  constexpr int KS = K / 32, NT = N / 16;
  constexpr int BM = 400, NG = 7;
  constexpr int CP = N + 8;
  __shared__ _Float16 Bs[N * K];
  __shared__ _Float16 VAs[16 * K];
  __shared__ _Float16 Cs[64 * CP];
  const int tid = threadIdx.x;
  const int lane = tid & 63, wid = tid >> 6;
  const int lr = lane & 15, lk = (lane >> 4) * 8;
  const int bm = blockIdx.x * BM;

  for (int i = tid * 8; i < N * K; i += 2048) {
    int row = i / K, k = i & (K - 1);
    f16x8 v = *(const f16x8*)&Bh[i];
    *(f16x8*)&Bs[(row * K + k) ^ ((row & 7) << 3)] = v;
  }
  for (int i = tid * 8; i < 16 * K; i += 2048) {
    int row = i / K, k = i & (K - 1);
    f16x8 v = *(const f16x8*)&VA[i];
    *(f16x8*)&VAs[(row * K + k) ^ ((row & 7) << 3)] = v;
  }
  __syncthreads();

  auto loadA = [&](int g, f16x8* areg) {
    int rlocal = g * 64 + wid * 16 + lr;
    int row = bm + rlocal;
    if (rlocal < BM && row < M) {
      const AT* arow = A + (size_t)row * K;
#pragma unroll
      for (int ks = 0; ks < KS; ++ks) {
        if constexpr (std::is_same<AT, float>::value) {
          float4 v0 = *(const float4*)&arow[ks * 32 + lk];
          float4 v1 = *(const float4*)&arow[ks * 32 + lk + 4];
          f16x8 t;
          t[0] = (_Float16)v0.x; t[1] = (_Float16)v0.y; t[2] = (_Float16)v0.z; t[3] = (_Float16)v0.w;
          t[4] = (_Float16)v1.x; t[5] = (_Float16)v1.y; t[6] = (_Float16)v1.z; t[7] = (_Float16)v1.w;
          areg[ks] = t;
        } else {
          areg[ks] = *(const f16x8*)&arow[ks * 32 + lk];
        }
      }
    } else {
#pragma unroll
      for (int ks = 0; ks < KS; ++ks) areg[ks] = (f16x8){};
    }
  };

  f16x8 a[KS], an[KS];
  loadA(0, a);
  const int rl0 = wid * 16 + (lane >> 4) * 4;

  for (int g = 0; g < NG; ++g) {
    if (g + 1 < NG) loadA(g + 1, an);

    f32x4 accv = (f32x4){0.f, 0.f, 0.f, 0.f};
#pragma unroll
    for (int ks = 0; ks < KS; ++ks) {
      f16x8 bv = *(const f16x8*)&VAs[(lr * K + ks * 32 + lk) ^ ((lr & 7) << 3)];
      accv = __builtin_amdgcn_mfma_f32_16x16x32_f16(a[ks], bv, accv, 0, 0, 0);
    }

    f32x4 acc[NT];
#pragma unroll
    for (int nt = 0; nt < NT; ++nt) acc[nt] = (f32x4){0.f, 0.f, 0.f, 0.f};
#pragma unroll
    for (int nt = 0; nt < NT; ++nt) {
      int brow = nt * 16 + lr;
#pragma unroll
      for (int ks = 0; ks < KS; ++ks) {
        f16x8 b = *(const f16x8*)&Bs[(brow * K + ks * 32 + lk) ^ ((brow & 7) << 3)];
        acc[nt] = __builtin_amdgcn_mfma_f32_16x16x32_f16(a[ks], b, acc[nt], 0, 0, 0);
      }
    }

#pragma unroll
    for (int r = 0; r < 4; ++r) {
      int rl = rl0 + r;
#pragma unroll
      for (int nt = 0; nt < NT; ++nt) Cs[rl * CP + nt * 16 + lr] = (_Float16)acc[nt][r];
      int rlocal = g * 64 + rl;
      int row = bm + rlocal;
      if (rlocal < BM && row < M) {
        if (lr < H) asrc[row * H + lr] = accv[r];
        else if (lr < 2 * H) adst[row * H + lr - H] = accv[r];
      }
    }
    __syncthreads();

    int rmax = min(64, min(BM - g * 64, M - (bm + g * 64)));
    if (rmax > 0) {
      int nch = rmax * (N / 8);
      for (int q = tid; q < nch; q += 256) {
        int row = q / (N / 8), c8 = q % (N / 8);
        f16x8 v = *(const f16x8*)&Cs[row * CP + c8 * 8];
        *(f16x8*)&C[(size_t)(bm + g * 64 + row) * N + c8 * 8] = v;
      }
    }
    __syncthreads();
#pragma unroll
    for (int ks = 0; ks < KS; ++ks) a[ks] = an[ks];
  }
}

// ------------- layer-1 aggregation: one WAVE per node, 8-deep gather pipeline ---
__global__ __launch_bounds__(256) void agg1_kernel(const _Float16* __restrict__ hmat,
    const float* __restrict__ asrc, const float* __restrict__ adst,
    const int* __restrict__ offsets, const int* __restrict__ esrc,
    const float* __restrict__ bias, _Float16* __restrict__ outv) {
  const int lane = threadIdx.x & 63, wid = threadIdx.x >> 6;
  const int node = blockIdx.x * 4 + wid;
  if (node >= NNODES) return;
  const int h = lane >> 4;
  const int start = offsets[node];
  const int end = offsets[node + 1];
  const float adn = adst[node * 4 + h];
  const _Float16* hbase = hmat + lane * 4;
  float acc[4] = {0.f, 0.f, 0.f, 0.f};
  float s = 0.f;
  int j = start;
  for (; j + 8 <= end; j += 8) {
    int sv[8];
#pragma unroll
    for (int t = 0; t < 8; ++t) sv[t] = esrc[j + t];
    f16x4 vv[8];
#pragma unroll
    for (int t = 0; t < 8; ++t) vv[t] = *(const f16x4*)&hbase[(size_t)sv[t] * 256];
    _Float16 ph[8];
#pragma unroll
    for (int t = 0; t < 8; ++t) {
      float v = asrc[sv[t] * 4 + h] + adn;
      v = (v > 0.f) ? v : 0.2f * v;
      float p = __expf(v);
      s += p;
      ph[t] = (_Float16)p;
    }
#pragma unroll
    for (int t = 0; t < 8; ++t)
#pragma unroll
      for (int k = 0; k < 4; ++k)
        acc[k] = fmaf((float)vv[t][k], (float)ph[t], acc[k]);  // v_fma_mix_f32
  }
  for (; j < end; ++j) {
    int sv = esrc[j];
    f16x4 vv = *(const f16x4*)&hbase[(size_t)sv * 256];
    float v = asrc[sv * 4 + h] + adn;
    v = (v > 0.f) ? v : 0.2f * v;
    float p = __expf(v);
    s += p;
    _Float16 phs = (_Float16)p;
#pragma unroll
    for (int k = 0; k < 4; ++k) acc[k] = fmaf((float)vv[k], (float)phs, acc[k]);
  }
  float inv = 1.f / (s + 1e-16f);
  f16x4 ho;
#pragma unroll
  for (int k = 0; k < 4; ++k)
    ho[k] = (_Float16)fmaxf(fmaf(acc[k], inv, bias[lane * 4 + k]), 0.f);
  *(f16x4*)&outv[(size_t)node * 256 + lane * 4] = ho;
}

// ------------- layer-2 aggregation: node per 16-lane group, 8-deep, f16 out -----
__global__ __launch_bounds__(256) void agg2_kernel(const _Float16* __restrict__ hmat,
    const float* __restrict__ asrc, const float* __restrict__ adst,
    const int* __restrict__ offsets, const int* __restrict__ esrc,
    const float* __restrict__ bias, _Float16* __restrict__ outv) {
  const int lane = threadIdx.x & 63, wid = threadIdx.x >> 6;
  const int g = lane >> 4, q = lane & 15;
  const int node = blockIdx.x * 16 + wid * 4 + g;
  if (node >= NNODES) return;
  const int start = offsets[node];
  const int end = offsets[node + 1];
  const float adn = adst[node];
  const _Float16* hbase = hmat + q * 4;
  float acc[4] = {0.f, 0.f, 0.f, 0.f};
  float s = 0.f;
  int j = start;
  for (; j + 8 <= end; j += 8) {
    int sv[8];
#pragma unroll
    for (int t = 0; t < 8; ++t) sv[t] = esrc[j + t];
    f16x4 v[8];
#pragma unroll
    for (int t = 0; t < 8; ++t) v[t] = *(const f16x4*)&hbase[(size_t)sv[t] * 64];
#pragma unroll
    for (int t = 0; t < 8; ++t) {
      float x = asrc[sv[t]] + adn;
      x = (x > 0.f) ? x : 0.2f * x;
      float p = __expf(x);
      s += p;
      _Float16 phs = (_Float16)p;
#pragma unroll
      for (int k = 0; k < 4; ++k) acc[k] = fmaf((float)v[t][k], (float)phs, acc[k]);
    }
  }
  for (; j < end; ++j) {
    int sv = esrc[j];
    f16x4 v = *(const f16x4*)&hbase[(size_t)sv * 64];
    float x = asrc[sv] + adn;
    x = (x > 0.f) ? x : 0.2f * x;
    float p = __expf(x);
    s += p;
    _Float16 phs = (_Float16)p;
#pragma unroll
    for (int k = 0; k < 4; ++k) acc[k] = fmaf((float)v[k], (float)phs, acc[k]);
  }
  float inv = 1.f / (s + 1e-16f);
  f16x4 ho;
#pragma unroll
  for (int k = 0; k < 4; ++k)
    ho[k] = (_Float16)fmaxf(fmaf(acc[k], inv, bias[q * 4 + k]), 0.f);
  *(f16x4*)&outv[(size_t)node * 64 + q * 4] = ho;
}

// ---------------- fused global mean pool (f16 input, fp32 accumulate) -----------
__global__ __launch_bounds__(256) void pool_kernel(const _Float16* __restrict__ g2,
    const int* __restrict__ batch, float* __restrict__ out, int n) {
  const int gid = blockIdx.x;
  const int lane = threadIdx.x & 63, w = threadIdx.x >> 6;
  int lo = 0, hi = n;
  while (lo < hi) { int mid = (lo + hi) >> 1; if (batch[mid] < gid) lo = mid + 1; else hi = mid; }
  int lb = lo;
  hi = n;
  while (lo < hi) { int mid = (lo + hi) >> 1; if (batch[mid] < gid + 1) lo = mid + 1; else hi = mid; }
  int ub = lo;
  float acc = 0.f;
  for (int i = lb + w; i < ub; i += 4) acc += (float)g2[(size_t)i * 64 + lane];
  __shared__ float red[4][64];
  red[w][lane] = acc;
  __syncthreads();
  if (threadIdx.x < 64) {
    float sum = (red[0][lane] + red[1][lane]) + (red[2][lane] + red[3][lane]);
    float cnt = fmaxf((float)(ub - lb), 1.f);
    out[gid * 64 + lane] = sum / cnt;
  }
}

// ---------------- launcher ----------------
extern "C" void kernel_launch(void* const* d_in, const int* in_sizes, int n_in,
                              void* d_out, int out_size, void* d_ws, size_t ws_size,
                              hipStream_t stream) {
  const float* x      = (const float*)d_in[0];
  const float* w1     = (const float*)d_in[1];
  const float* a_src1 = (const float*)d_in[2];
  const float* a_dst1 = (const float*)d_in[3];
  const float* b1     = (const float*)d_in[4];
  const float* w2     = (const float*)d_in[5];
  const float* a_src2 = (const float*)d_in[6];
  const float* a_dst2 = (const float*)d_in[7];
  const float* b2     = (const float*)d_in[8];
  const int*   src    = (const int*)d_in[9];
  const int*   dst    = src + NEDGES;
  const int*   batch  = (const int*)d_in[10];
  float* out = (float*)d_out;

  const int N = NNODES, E = NEDGES;

  char* wsb = (char*)d_ws;
  size_t off = 0;
  auto alloc = [&](size_t bytes) {
    void* p = wsb + off;
    off = (off + bytes + 255) & ~(size_t)255;
    return p;
  };
  _Float16* h1h = (_Float16*)alloc((size_t)N * 256 * 2);
  _Float16* g1h = (_Float16*)alloc((size_t)N * 256 * 2);
  _Float16* h2h = (_Float16*)alloc((size_t)N * 64 * 2);
  _Float16* g2h = (_Float16*)alloc((size_t)N * 64 * 2);
  float* as1    = (float*)alloc((size_t)N * 4 * 4);
  float* ad1    = (float*)alloc((size_t)N * 4 * 4);
  float* as2    = (float*)alloc((size_t)N * 4);
  float* ad2    = (float*)alloc((size_t)N * 4);
  int* pre      = (int*)alloc((size_t)N * 4);
  int* bsum     = (int*)alloc((size_t)NBKT * 4);
  int* offsets  = (int*)alloc((size_t)(N + 1) * 4);
  int* esrc     = (int*)alloc((size_t)E * 4);
  unsigned* part= (unsigned*)alloc((size_t)8 * NBKT * CAP * 4);
  int* gcur     = (int*)alloc((size_t)8 * NBKT * 16 * 4);
  _Float16* w1h = (_Float16*)alloc((size_t)256 * 128 * 2);
  _Float16* w2h = (_Float16*)alloc((size_t)64 * 256 * 2);
  _Float16* va1 = (_Float16*)alloc((size_t)16 * 128 * 2);
  _Float16* va2 = (_Float16*)alloc((size_t)16 * 256 * 2);

  // ---- front: convert+GEMV || edge partition ----
  hipMemsetAsync(gcur, 0, (size_t)8 * NBKT * 16 * 4, stream);
  front1<<<202 + (E + EPB - 1) / EPB, 256, 0, stream>>>(
      w1, w2, a_src1, a_dst1, a_src2, a_dst2, w1h, w2h, va1, va2,
      src, dst, part, gcur, E);

  // ---- CSR build ----
  bucketB1p<<<NBKT, 256, 0, stream>>>(part, gcur, pre, bsum, N);
  bucketB2<<<NBKT, 256, 0, stream>>>(part, gcur, pre, bsum, offsets, esrc, N, E);

  // ---- layer 1 ----
  gemm_mfma<128, 256, float><<<250, 256, 0, stream>>>(
      x, w1h, va1, h1h, N, as1, ad1);
  agg1_kernel<<<(N + 3) / 4, 256, 0, stream>>>(h1h, as1, ad1, offsets, esrc, b1, g1h);

  // ---- layer 2 ----
  gemm_mfma<256, 64, _Float16><<<250, 256, 0, stream>>>(
      g1h, w2h, va2, h2h, N, as2, ad2);
  agg2_kernel<<<(N + 15) / 16, 256, 0, stream>>>(h2h, as2, ad2, offsets, esrc, b2, g2h);

  // ---- pool ----
  pool_kernel<<<NGRAPH, 256, 0, stream>>>(g2h, batch, out, N);
}